// Round 7
// baseline (682.602 us; speedup 1.0000x reference)
//
#include <hip/hip_runtime.h>
#include <math.h>

#define NV 4096      // variable nodes
#define MC 2048      // check nodes
#define DV 3
#define DC 6
#define NE (NV * DV) // 12288 edges
#define NB 2048      // batch
#define NITER 5
#define TPB 1024     // 16 waves/block; 2 blocks/CU -> 32 waves/CU

// Build per-check-node edge lists (slot order arbitrary due to atomics).
__global__ __launch_bounds__(256) void build_cn(const int* __restrict__ cn_idx,
                                                int* __restrict__ cn_edges,
                                                int* __restrict__ cn_cnt) {
    int e = blockIdx.x * 256 + threadIdx.x;
    if (e < NE) {
        int m = cn_idx[e];
        int slot = atomicAdd(&cn_cnt[m], 1);
        cn_edges[m * DC + slot] = e;
    }
}

// Sort each CN's 6 edges ascending (deterministic, matches ref edge order) and
// emit packed table rows: tbl[m*6+j] = {vn_index, bits(edge_weight)}.
__global__ __launch_bounds__(256) void sort_cn(int* __restrict__ cn_edges,
                                               const float* __restrict__ ew,
                                               uint2* __restrict__ tbl) {
    int m = blockIdx.x * 256 + threadIdx.x;
    if (m < MC) {
        int v[DC];
        for (int j = 0; j < DC; ++j) v[j] = cn_edges[m * DC + j];
        for (int i = 1; i < DC; ++i) {
            int key = v[i]; int j = i - 1;
            while (j >= 0 && v[j] > key) { v[j + 1] = v[j]; --j; }
            v[j + 1] = key;
        }
        for (int j = 0; j < DC; ++j) {
            int e = v[j];
            tbl[m * DC + j] = make_uint2((unsigned)(e / DV),
                                         __float_as_uint(ew[e]));
        }
    }
}

// Fused single-phase BP: per-thread CN messages live in REGISTERS across
// iterations (each thread owns the same 2 CNs all 5 iters). LDS holds only
// the per-VN totals, double-buffered (2 x 16 KB). Per iter per thread:
// 12 random reads (prev totals) + 12 ds_add_f32 (next totals) + 4 re-init
// writes -- vs 48 LDS ops for the two-phase version. CN math in product
// domain (P+/P-, 3 trans/edge); clip == ref's float32(1-1e-7) = 1-2^-23 via
// den = max(Pp-Pm, 2^-23*Pp). Sign via bit parity (exact).
__global__ __launch_bounds__(TPB, 8) void bp_fused(const float* __restrict__ noise_r,
                                                   const uint2* __restrict__ tbl,
                                                   float* __restrict__ out) {
    __shared__ float buf[2][NV];
    const int b = blockIdx.x;
    const int t = threadIdx.x;

    const float NO   = (float)0.3981071705534972;          // 1/(R*2*10^(EbNo/10))
    const float NSTD = sqrtf((float)(0.3981071705534972 * 0.5));

    // ---- channel LLRs; both buffers start as llr ----
    float llr[NV / TPB];
    const float* nb = noise_r + (size_t)b * NV;
#pragma unroll
    for (int k = 0; k < NV / TPB; ++k) {
        int n = t + TPB * k;
        float y = 1.0f + NSTD * nb[n];
        float l = (4.0f * y) / NO;
        llr[k] = l;
        buf[0][n] = l;
        buf[1][n] = l;
    }

    // per-thread CN outgoing messages (prev iter); 0 before first iter
    float msg_reg[MC / TPB][DC];
#pragma unroll
    for (int c = 0; c < MC / TPB; ++c)
#pragma unroll
        for (int j = 0; j < DC; ++j) msg_reg[c][j] = 0.0f;

    __syncthreads();

    for (int it = 0; it < NITER; ++it) {
        float* __restrict__ src = buf[it & 1];
        float* __restrict__ dst = buf[(it + 1) & 1];

#pragma unroll
        for (int c = 0; c < MC / TPB; ++c) {
            const int m = t + TPB * c;
            // table row: 6 x uint2 = 48 B = 3 x uint4 (L2-resident)
            const uint4* tp = (const uint4*)(tbl + m * DC);
            uint4 q0 = tp[0], q1 = tp[1], q2 = tp[2];
            unsigned vn[DC] = {q0.x, q0.z, q1.x, q1.z, q2.x, q2.z};
            unsigned wb[DC] = {q0.y, q0.w, q1.y, q1.w, q2.y, q2.w};

            float a[DC], bb[DC];
            unsigned spack = 0u;
#pragma unroll
            for (int j = 0; j < DC; ++j) {
                float tot = src[vn[j]];
                float mw  = (tot - msg_reg[c][j]) * __uint_as_float(wb[j]);
                float u   = __expf(-fabsf(mw));
                a[j]  = 1.0f + u;
                bb[j] = 1.0f - u;
                spack |= ((__float_as_uint(mw) >> 31) & 1u) << j;
            }
            unsigned par = __popc(spack) & 1u;

            // suffix then running-prefix exclusion products
            float sp[DC], sm[DC];
            sp[DC - 1] = 1.0f; sm[DC - 1] = 1.0f;
#pragma unroll
            for (int j = DC - 2; j >= 0; --j) {
                sp[j] = sp[j + 1] * a[j + 1];
                sm[j] = sm[j + 1] * bb[j + 1];
            }
            float rp = 1.0f, rm = 1.0f;
#pragma unroll
            for (int j = 0; j < DC; ++j) {
                float Pp  = rp * sp[j];
                float Pm  = rm * sm[j];
                float num = Pp + Pm;
                float den = fmaxf(Pp - Pm, 0x1.0p-23f * Pp);   // == ref clip 1-2^-23
                float val = __logf(__fdividef(num, den));      // >= 0
                unsigned sg = ((par ^ (spack >> j)) & 1u) << 31;
                float sval = __uint_as_float(__float_as_uint(val) | sg);
                msg_reg[c][j] = sval;
                atomicAdd(&dst[vn[j]], sval);                  // ds_add_f32
                rp *= a[j];
                rm *= bb[j];
            }
        }
        __syncthreads();

        if (it < NITER - 1) {
            // src becomes the accumulation target of iter it+1: re-init to llr
#pragma unroll
            for (int k = 0; k < NV / TPB; ++k) src[t + TPB * k] = llr[k];
            __syncthreads();
        }
    }

    // result = dst of final iter = buf[(NITER) & 1] = buf[1]
#pragma unroll
    for (int k = 0; k < NV / TPB; ++k) {
        int n = t + TPB * k;
        out[(size_t)b * NV + n] = buf[NITER & 1][n];
    }
}

extern "C" void kernel_launch(void* const* d_in, const int* in_sizes, int n_in,
                              void* d_out, int out_size, void* d_ws, size_t ws_size,
                              hipStream_t stream) {
    const float* noise_r = (const float*)d_in[0];
    // d_in[1] = noise_i (unused by reference)
    const float* ew      = (const float*)d_in[2];
    // d_in[3] = vn_idx: known structure e // 3 (edges contiguous per VN)
    const int*   cn_idx  = (const int*)d_in[4];
    float* out = (float*)d_out;

    int*   cn_edges = (int*)d_ws;                 // NE ints   (48 KB)
    int*   cn_cnt   = cn_edges + NE;              // MC ints   (8 KB)
    uint2* tbl      = (uint2*)(cn_cnt + MC);      // MC*6 uint2 (96 KB), 16B-aligned

    hipMemsetAsync(cn_cnt, 0, MC * sizeof(int), stream);
    build_cn<<<(NE + 255) / 256, 256, 0, stream>>>(cn_idx, cn_edges, cn_cnt);
    sort_cn<<<(MC + 255) / 256, 256, 0, stream>>>(cn_edges, ew, tbl);
    bp_fused<<<NB, TPB, 0, stream>>>(noise_r, tbl, out);
}

// Round 8
// 159.618 us; speedup vs baseline: 4.2765x; 4.2765x over previous
//
#include <hip/hip_runtime.h>
#include <math.h>

#define NV 4096      // variable nodes
#define MC 2048      // check nodes
#define DV 3
#define DC 6
#define NE (NV * DV) // 12288 edges
#define NB 2048      // batch
#define NITER 5
#define TPB 1024     // 16 waves/block; 2 blocks/CU -> 32 waves/CU

// Build per-check-node edge lists (slot order arbitrary due to atomics).
__global__ __launch_bounds__(256) void build_cn(const int* __restrict__ cn_idx,
                                                int* __restrict__ cn_edges,
                                                int* __restrict__ cn_cnt) {
    int e = blockIdx.x * 256 + threadIdx.x;
    if (e < NE) {
        int m = cn_idx[e];
        int slot = atomicAdd(&cn_cnt[m], 1);
        cn_edges[m * DC + slot] = e;
    }
}

// Sort each CN's 6 edges ascending -> deterministic, matches ref edge order.
__global__ __launch_bounds__(256) void sort_cn(int* __restrict__ cn_edges) {
    int m = blockIdx.x * 256 + threadIdx.x;
    if (m < MC) {
        int v[DC];
        for (int j = 0; j < DC; ++j) v[j] = cn_edges[m * DC + j];
        for (int i = 1; i < DC; ++i) {
            int key = v[i]; int j = i - 1;
            while (j >= 0 && v[j] > key) { v[j + 1] = v[j]; --j; }
            v[j + 1] = key;
        }
        for (int j = 0; j < DC; ++j) cn_edges[m * DC + j] = v[j];
    }
}

// One workgroup per batch element; all E messages live in LDS (48 KB),
// edge-major (bank-uniform for the random CN gather; stride-3 conflict-free
// for the VN side). Two-phase with barriers — no LDS atomics (R6 lesson).
//
// CN update in product domain: u = e^{-|mw|}; Pp/Pm = exclusion products of
// (1+u)/(1-u); 2*atanh(Pm/Pp) = ln((Pp+Pm)/(Pp-Pm)). Reference clips mag at
// float32(1-1e-7) = 1-2^-23 exactly; branchless equivalent:
// den = max(Pp-Pm, 2^-23*Pp). Sign via bit-parity XOR (exact == ref mod-2).
// [Numerics proven in R5: absmax 1.0]
__global__ __launch_bounds__(TPB, 8) void bp_iter(const float* __restrict__ noise_r,
                                                  const float* __restrict__ ew,
                                                  const int* __restrict__ cn_edges,
                                                  float* __restrict__ out) {
    __shared__ float msg[NE];
    const int b = blockIdx.x;
    const int t = threadIdx.x;

    const float NO   = (float)0.3981071705534972;          // 1/(R*2*10^(EbNo/10))
    const float NSTD = sqrtf((float)(0.3981071705534972 * 0.5));

    // Hoist per-CN edge lists into registers (12 VGPR; one-time global read).
    int eidx[MC / TPB][DC];
#pragma unroll
    for (int c = 0; c < MC / TPB; ++c)
#pragma unroll
        for (int j = 0; j < DC; ++j)
            eidx[c][j] = cn_edges[(t + TPB * c) * DC + j];

    float llr[NV / TPB];
    const float* nb = noise_r + (size_t)b * NV;
#pragma unroll
    for (int k = 0; k < NV / TPB; ++k) {
        int n = t + TPB * k;
        float y = 1.0f + NSTD * nb[n];
        float l = (4.0f * y) / NO;
        llr[k] = l;
        msg[3 * n + 0] = l * ew[3 * n + 0];
        msg[3 * n + 1] = l * ew[3 * n + 1];
        msg[3 * n + 2] = l * ew[3 * n + 2];
    }
    __syncthreads();

    for (int it = 0; it < NITER; ++it) {
        // ---- CN update: each thread owns 2 check nodes ----
#pragma unroll
        for (int c = 0; c < MC / TPB; ++c) {
            float a[DC], bb[DC];
            unsigned spack = 0u;
#pragma unroll
            for (int j = 0; j < DC; ++j) {
                float mw = msg[eidx[c][j]];
                float u  = __expf(-fabsf(mw));
                a[j]  = 1.0f + u;
                bb[j] = 1.0f - u;
                spack |= ((__float_as_uint(mw) >> 31) & 1u) << j;
            }
            unsigned par = __popc(spack) & 1u;

            // suffix products (right-to-left), then running prefix
            float sp[DC], sm[DC];
            sp[DC - 1] = 1.0f; sm[DC - 1] = 1.0f;
#pragma unroll
            for (int j = DC - 2; j >= 0; --j) {
                sp[j] = sp[j + 1] * a[j + 1];
                sm[j] = sm[j + 1] * bb[j + 1];
            }
            float rp = 1.0f, rm = 1.0f;
#pragma unroll
            for (int j = 0; j < DC; ++j) {
                float Pp  = rp * sp[j];
                float Pm  = rm * sm[j];
                float num = Pp + Pm;
                float den = fmaxf(Pp - Pm, 0x1.0p-23f * Pp);   // == ref clip 1-2^-23
                float val = __logf(__fdividef(num, den));      // >= 0
                unsigned sg = ((par ^ (spack >> j)) & 1u) << 31;
                msg[eidx[c][j]] = __uint_as_float(__float_as_uint(val) | sg);
                rp *= a[j];
                rm *= bb[j];
            }
        }
        __syncthreads();

        // ---- VN update: each thread owns 4 variable nodes ----
        if (it < NITER - 1) {
#pragma unroll
            for (int k = 0; k < NV / TPB; ++k) {
                int n = t + TPB * k;
                float c0 = msg[3 * n + 0];
                float c1 = msg[3 * n + 1];
                float c2 = msg[3 * n + 2];
                float tot = llr[k] + (c0 + c1 + c2);
                msg[3 * n + 0] = (tot - c0) * ew[3 * n + 0];
                msg[3 * n + 1] = (tot - c1) * ew[3 * n + 1];
                msg[3 * n + 2] = (tot - c2) * ew[3 * n + 2];
            }
            __syncthreads();
        } else {
#pragma unroll
            for (int k = 0; k < NV / TPB; ++k) {
                int n = t + TPB * k;
                float c0 = msg[3 * n + 0];
                float c1 = msg[3 * n + 1];
                float c2 = msg[3 * n + 2];
                out[(size_t)b * NV + n] = llr[k] + (c0 + c1 + c2);
            }
        }
    }
}

extern "C" void kernel_launch(void* const* d_in, const int* in_sizes, int n_in,
                              void* d_out, int out_size, void* d_ws, size_t ws_size,
                              hipStream_t stream) {
    const float* noise_r = (const float*)d_in[0];
    // d_in[1] = noise_i (unused by reference)
    const float* ew      = (const float*)d_in[2];
    // d_in[3] = vn_idx: known structure e // 3 (edges contiguous per VN)
    const int*   cn_idx  = (const int*)d_in[4];
    float* out = (float*)d_out;

    int* cn_edges = (int*)d_ws;        // NE ints
    int* cn_cnt   = cn_edges + NE;     // MC ints

    hipMemsetAsync(cn_cnt, 0, MC * sizeof(int), stream);
    build_cn<<<(NE + 255) / 256, 256, 0, stream>>>(cn_idx, cn_edges, cn_cnt);
    sort_cn<<<(MC + 255) / 256, 256, 0, stream>>>(cn_edges);
    bp_iter<<<NB, TPB, 0, stream>>>(noise_r, ew, cn_edges, out);
}